// Round 5
// baseline (1555.695 us; speedup 1.0000x reference)
//
#include <hip/hip_runtime.h>
#include <hip/hip_bf16.h>
#include <float.h>

// Problem constants (OSG_C_29987461660961)
#define NTOK 2048
#define FDIM 1024
#define HDIM 512
#define EDIM 256
#define BATCH 2
#define KSEG 30
#define NP1 2049
static const size_t ST2 = (size_t)NP1 * NP1;   // Sp per-batch element count

// ---------------------------------------------------------------------------
// Shared NT GEMM: C[i][j] = sum_k A[i*lda+k]*B[j*ldb+k]  (+bias / relu / D-xform)
// ---------------------------------------------------------------------------
template<int MODE>
__global__ __launch_bounds__(256)
void gemm_nt(const float* __restrict__ A, int lda, size_t strideA,
             const float* __restrict__ Bm, int ldb, size_t strideB,
             const float* __restrict__ bias,
             float* __restrict__ C, int ldc, size_t strideC,
             int K, const float* __restrict__ dvec)
{
    __shared__ float As[32][68];
    __shared__ float Bs[32][68];
    const int z = blockIdx.z;
    const float* Ab = A + (size_t)z * strideA;
    const float* Bb = Bm + (size_t)z * strideB;
    float* Cb = C + (size_t)z * strideC;

    const int t = threadIdx.x;
    const int tx = t & 15, ty = t >> 4;
    const int lrow = t >> 3, lkv = t & 7;
    const int by = blockIdx.y, bx = blockIdx.x;

    float acc[4][4] = {};
    const int ktiles = K >> 5;
    for (int kt = 0; kt < ktiles; ++kt) {
#pragma unroll
        for (int h = 0; h < 2; ++h) {
            const int r = lrow + h * 32;
            const float4 av = *(const float4*)(Ab + (size_t)(by * 64 + r) * lda + kt * 32 + lkv * 4);
            As[lkv * 4 + 0][r] = av.x; As[lkv * 4 + 1][r] = av.y;
            As[lkv * 4 + 2][r] = av.z; As[lkv * 4 + 3][r] = av.w;
            const float4 bv = *(const float4*)(Bb + (size_t)(bx * 64 + r) * ldb + kt * 32 + lkv * 4);
            Bs[lkv * 4 + 0][r] = bv.x; Bs[lkv * 4 + 1][r] = bv.y;
            Bs[lkv * 4 + 2][r] = bv.z; Bs[lkv * 4 + 3][r] = bv.w;
        }
        __syncthreads();
#pragma unroll
        for (int kk = 0; kk < 32; ++kk) {
            const float4 a = *(const float4*)&As[kk][ty * 4];
            const float4 b = *(const float4*)&Bs[kk][tx * 4];
            const float ar[4] = {a.x, a.y, a.z, a.w};
            const float br[4] = {b.x, b.y, b.z, b.w};
#pragma unroll
            for (int i = 0; i < 4; ++i)
#pragma unroll
                for (int j = 0; j < 4; ++j)
                    acc[i][j] = fmaf(ar[i], br[j], acc[i][j]);
        }
        __syncthreads();
    }

    const int row0 = by * 64 + ty * 4;
    const int col0 = bx * 64 + tx * 4;
    if (MODE == 2) {
        float di[4], dj[4];
#pragma unroll
        for (int i = 0; i < 4; ++i) di[i] = dvec[z * NTOK + row0 + i];
#pragma unroll
        for (int j = 0; j < 4; ++j) dj[j] = dvec[z * NTOK + col0 + j];
#pragma unroll
        for (int i = 0; i < 4; ++i) {
            float4 v;
            float o[4];
#pragma unroll
            for (int j = 0; j < 4; ++j) {
                const float den = sqrtf(fmaxf(di[i] * dj[j], 1e-8f));
                o[j] = 0.5f * (1.0f - acc[i][j] / den);
            }
            v.x = o[0]; v.y = o[1]; v.z = o[2]; v.w = o[3];
            *(float4*)(Cb + (size_t)(row0 + i) * ldc + col0) = v;
        }
    } else {
#pragma unroll
        for (int i = 0; i < 4; ++i) {
            float o[4];
#pragma unroll
            for (int j = 0; j < 4; ++j) {
                float v = acc[i][j] + bias[col0 + j];
                if (MODE == 0) v = fmaxf(v, 0.0f);
                o[j] = v;
            }
            float4 v4; v4.x = o[0]; v4.y = o[1]; v4.z = o[2]; v4.w = o[3];
            *(float4*)(Cb + (size_t)(row0 + i) * ldc + col0) = v4;
        }
    }
}

__global__ __launch_bounds__(256)
void rownorm_kernel(const float* __restrict__ e, float* __restrict__ dvec)
{
    const int wid = (blockIdx.x * 256 + threadIdx.x) >> 6;
    const int lane = threadIdx.x & 63;
    if (wid >= BATCH * NTOK) return;
    const float4 v = *(const float4*)(e + (size_t)wid * EDIM + lane * 4);
    float s = v.x * v.x + v.y * v.y + v.z * v.z + v.w * v.w;
#pragma unroll
    for (int off = 32; off; off >>= 1) s += __shfl_xor(s, off);
    if (lane == 0) dvec[wid] = s;
}

// Row-wise inclusive scan of D (f32) into Sp rows 1..N (f64). Sp[r][0]=0.
__global__ __launch_bounds__(256)
void sat_row_kernel(const float* __restrict__ D, double* __restrict__ Sp)
{
    const int b = blockIdx.y;
    const int r = blockIdx.x + 1;
    const float* drow = D + (size_t)b * NTOK * NTOK + (size_t)(r - 1) * NTOK;
    double* sprow = Sp + (size_t)b * ST2 + (size_t)r * NP1;
    const int t = threadIdx.x, lane = t & 63, wv = t >> 6;
    __shared__ double wtot[4];
    double carry = 0.0;
    if (t == 0) sprow[0] = 0.0;
    for (int ch = 0; ch < NTOK / 256; ++ch) {
        double v = (double)drow[ch * 256 + t];
#pragma unroll
        for (int d = 1; d < 64; d <<= 1) {
            const double u = __shfl_up(v, (unsigned)d, 64);
            if (lane >= d) v += u;
        }
        if (lane == 63) wtot[wv] = v;
        __syncthreads();
        double pre = carry;
        for (int ww = 0; ww < wv; ++ww) pre += wtot[ww];
        const double tot = carry + wtot[0] + wtot[1] + wtot[2] + wtot[3];
        sprow[ch * 256 + t + 1] = v + pre;
        __syncthreads();
        carry = tot;
    }
}

// Column cumsum of Sp in 3 phases (strips of 256 rows).
__global__ void satc1(const double* __restrict__ Sp, double* __restrict__ aux)
{
    const int b = blockIdx.z, s = blockIdx.y;
    const int c = blockIdx.x * 256 + threadIdx.x;
    if (c > NTOK) return;
    const double* sp = Sp + (size_t)b * ST2;
    double tt = 0.0;
    const int r0 = s * 256 + 1;
    for (int r = r0; r < r0 + 256; ++r) tt += sp[(size_t)r * NP1 + c];
    aux[(size_t)(b * 8 + s) * NP1 + c] = tt;
}
__global__ void satc2(double* __restrict__ aux)
{
    const int b = blockIdx.y;
    const int c = blockIdx.x * 256 + threadIdx.x;
    if (c > NTOK) return;
    double run = 0.0;
    for (int s = 0; s < 8; ++s) {
        const size_t id = (size_t)(b * 8 + s) * NP1 + c;
        const double tt = aux[id]; aux[id] = run; run += tt;
    }
}
__global__ void satc3(double* __restrict__ Sp, const double* __restrict__ aux)
{
    const int b = blockIdx.z, s = blockIdx.y;
    const int c = blockIdx.x * 256 + threadIdx.x;
    if (c > NTOK) return;
    double* sp = Sp + (size_t)b * ST2;
    if (s == 0) sp[c] = 0.0;
    double run = aux[(size_t)(b * 8 + s) * NP1 + c];
    const int r0 = s * 256 + 1;
    for (int r = r0; r < r0 + 256; ++r) {
        const size_t id = (size_t)r * NP1 + c;
        run += sp[id];
        sp[id] = run;
    }
}

__global__ void diag_kernel(const double* __restrict__ Sp, double* __restrict__ dg)
{
    const int b = blockIdx.y;
    const int t = blockIdx.x * 256 + threadIdx.x;
    if (t <= NTOK) dg[b * NP1 + t] = Sp[(size_t)b * ST2 + (size_t)t * NP1 + t];
}

// Bsum[i][j] = diag[j+1] + diag[i] - 2*Sp[i][j+1] (f64 math -> f32), j >= i.
__global__ __launch_bounds__(256)
void bsum_kernel(const double* __restrict__ Sp, const double* __restrict__ dg,
                 float* __restrict__ Bsum, float* __restrict__ C0)
{
    const int b = blockIdx.y, i = blockIdx.x;
    const double* sprow = Sp + (size_t)b * ST2 + (size_t)i * NP1;
    const double* dgb = dg + (size_t)b * NP1;
    const double di = dgb[i];
    float* brow = Bsum + (size_t)b * NTOK * NTOK + (size_t)i * NTOK;
    for (int j = i + threadIdx.x; j < NTOK; j += 256) {
        const double v = dgb[j + 1] + di - 2.0 * sprow[j + 1];
        brow[j] = (float)v;
        if (j == NTOK - 1) C0[b * NTOK + i] = (float)v;
    }
}

// ---------------------------------------------------------------------------
// Flag-array sync: no RMWs, no counter tree. Block i of batch b owns
// flags[(b*128 + i)*4] (16B apart). Publish = one release store; wait =
// thread t polls flag t of its own batch in parallel (one global_load per
// wave per round). Publish-after-read ordering makes the 2-buffer C
// exchange race-free. flags memset to 0xFF (= -1) before launch.
// ---------------------------------------------------------------------------
#define DP_BX 128
#define DP_PAIRS 8

__device__ inline void cstore(float* p, float v)
{
    __hip_atomic_store(p, v, __ATOMIC_RELAXED, __HIP_MEMORY_SCOPE_AGENT);
}
__device__ inline float cload(const float* p)
{
    return __hip_atomic_load(p, __ATOMIC_RELAXED, __HIP_MEMORY_SCOPE_AGENT);
}

__device__ inline void wait_flags(const int* flagsb, int need)
{
    const int t = threadIdx.x;
    if (t < DP_BX) {
        const int* f = flagsb + t * 4;
        while (__hip_atomic_load(f, __ATOMIC_RELAXED, __HIP_MEMORY_SCOPE_AGENT) < need)
            __builtin_amdgcn_s_sleep(1);
    }
    __syncthreads();
    __builtin_amdgcn_fence(__ATOMIC_ACQUIRE, "agent");
}

__device__ inline void publish(int* myflag, int val)
{
    __syncthreads();   // drains each wave's vmcnt before s_barrier -> C stores visible
    if (threadIdx.x == 0)
        __hip_atomic_store(myflag, val, __ATOMIC_RELEASE, __HIP_MEMORY_SCOPE_AGENT);
}

// ---------------------------------------------------------------------------
// Fused DP: all 29 steps, Bsum upper-triangle parked in LDS.
// Grid (128, BATCH) x 256 threads, 8 row pairs (p, 2047-p) per block,
// 82KB LDS -> 1 block/CU, 256 blocks co-resident (cooperative launch).
// ---------------------------------------------------------------------------
__global__ __launch_bounds__(256)
void dp_fused_kernel(const float* __restrict__ Bsum,
                     float* __restrict__ Ca, float* __restrict__ Cb,
                     float* __restrict__ tsum, int* __restrict__ flags)
{
    __shared__ float rowbuf[DP_PAIRS][2052];
    __shared__ float cs[NTOK];
    __shared__ float acc[NTOK];
    const int b = blockIdx.y;
    const int t = threadIdx.x, lane = t & 63, wv = t >> 6;
    const float* Bb = Bsum + (size_t)b * NTOK * NTOK;
    const int pbase = blockIdx.x * DP_PAIRS;
    int* flagsb = flags + b * DP_BX * 4;
    int* myflag = flagsb + blockIdx.x * 4;

    // coalesced whole-block load of each pair-row (row i0 cols p.., then row i1)
    for (int pr = 0; pr < DP_PAIRS; ++pr) {
        const int p = pbase + pr;
        const int L0 = NTOK - p;
        const float* r0 = Bb + (size_t)p * NTOK + p;
        const float* r1 = Bb + (size_t)(NTOK - 1 - p) * NTOK;
        for (int idx = t; idx <= NTOK; idx += 256)
            rowbuf[pr][idx] = (idx < L0) ? r0[idx] : r1[idx - 1];
    }
    for (int j = t; j < NTOK; j += 256) acc[j] = 0.0f;
    __syncthreads();
    // C0[i] = Bsum[i][N-1]
    for (int pr = t; pr < DP_PAIRS; pr += 256) {
        const int p = pbase + pr;
        cstore(&Ca[b * NTOK + p], rowbuf[pr][NTOK - p - 1]);
        cstore(&Ca[b * NTOK + (NTOK - 1 - p)], rowbuf[pr][NTOK]);
    }
    publish(myflag, 0);

    const float* Cr = Ca;
    float* Cn = Cb;
    for (int k = 1; k < KSEG; ++k) {
        wait_flags(flagsb, k - 1);         // all blocks of batch b published step k-1
        const float* Crb = Cr + b * NTOK;
        for (int j = t; j < NTOK; j += 256)
            cs[j] = (j < NTOK - 1) ? cload(&Crb[j + 1]) : 0.0f;
        __syncthreads();
        const int jmax = NTOK - k;
        float* Cnb = Cn + b * NTOK;
#pragma unroll
        for (int u = 0; u < 2; ++u) {
            const int pr = wv * 2 + u;
            const int p = pbase + pr;
            const float* rb = rowbuf[pr];
            // ---- row i0 = p (always valid) ----
            {
                const int V = jmax - p;
                float mv[32];
                float mn = FLT_MAX;
#pragma unroll
                for (int c = 0; c < 32; ++c) {
                    const int idx = lane + c * 64;
                    float v = FLT_MAX;
                    if (idx < V) v = rb[idx] + cs[p + idx];
                    mv[c] = v;
                    mn = fminf(mn, v);
                }
#pragma unroll
                for (int off = 32; off; off >>= 1) mn = fminf(mn, __shfl_xor(mn, off));
                if (lane == 0) cstore(&Cnb[p], mn);
                float s = 0.0f;
#pragma unroll
                for (int c = 0; c < 32; ++c) {
                    const int idx = lane + c * 64;
                    float w = 0.0f;
                    if (idx < V) w = __expf(mn - mv[c]);
                    mv[c] = w;
                    s += w;
                }
#pragma unroll
                for (int off = 32; off; off >>= 1) s += __shfl_xor(s, off);
                const float inv = 1.0f / s;
#pragma unroll
                for (int c = 0; c < 32; ++c) {
                    const int idx = lane + c * 64;
                    if (idx < V) atomicAdd(&acc[p + idx], mv[c] * inv);
                }
            }
            // ---- row i1 = 2047-p (valid iff p >= k) ----
            const int i1 = NTOK - 1 - p;
            if (p >= k) {
                const int V = p + 1 - k;
                const int base = NTOK - p;
                float mv[16];
                float mn = FLT_MAX;
#pragma unroll
                for (int c = 0; c < 16; ++c) {
                    const int idx = lane + c * 64;
                    float v = FLT_MAX;
                    if (idx < V) v = rb[base + idx] + cs[i1 + idx];
                    mv[c] = v;
                    mn = fminf(mn, v);
                }
#pragma unroll
                for (int off = 32; off; off >>= 1) mn = fminf(mn, __shfl_xor(mn, off));
                if (lane == 0) cstore(&Cnb[i1], mn);
                float s = 0.0f;
#pragma unroll
                for (int c = 0; c < 16; ++c) {
                    const int idx = lane + c * 64;
                    float w = 0.0f;
                    if (idx < V) w = __expf(mn - mv[c]);
                    mv[c] = w;
                    s += w;
                }
#pragma unroll
                for (int off = 32; off; off >>= 1) s += __shfl_xor(s, off);
                const float inv = 1.0f / s;
#pragma unroll
                for (int c = 0; c < 16; ++c) {
                    const int idx = lane + c * 64;
                    if (idx < V) atomicAdd(&acc[i1 + idx], mv[c] * inv);
                }
            } else if (lane == 0) {
                cstore(&Cnb[i1], 0.0f);
            }
        }
        publish(myflag, k);                // after this block finished READING Cr
        float* tmp = (float*)Cr; Cr = Cn; Cn = tmp;
    }
    // merge per-block acc into global tsum (publish's syncthreads ordered us)
    float* ts = tsum + b * NTOK;
    for (int j = t; j < NTOK; j += 256) {
        const float v = acc[j];
        if (v != 0.0f) atomicAdd(&ts[j], v);
    }
}

// ---- fallback path (29 launches), kept in case cooperative launch fails ----
__global__ __launch_bounds__(256)
void dp_step_kernel(const float* __restrict__ Bsum, const float* __restrict__ Cprev,
                    float* __restrict__ Cnext, float* __restrict__ tsum, int kk)
{
    __shared__ float cs[NTOK];
    __shared__ float acc[NTOK];
    const int b = blockIdx.y;
    const int t = threadIdx.x, lane = t & 63, wv = t >> 6;
    const float* Cp = Cprev + b * NTOK;
    for (int j = t; j < NTOK; j += 256) {
        cs[j] = (j < NTOK - 1) ? Cp[j + 1] : 0.0f;
        acc[j] = 0.0f;
    }
    __syncthreads();
    const int jmax = NTOK - kk;
    const int w = blockIdx.x * 4 + wv;
    const float* Bb = Bsum + (size_t)b * NTOK * NTOK;
    float* Cn = Cnext + b * NTOK;
    const int rows[4] = { w, 1023 - w, 1024 + w, 2047 - w };
#pragma unroll
    for (int rr = 0; rr < 4; ++rr) {
        const int i = rows[rr];
        if (i >= jmax) { if (lane == 0) Cn[i] = 0.0f; continue; }
        const float* brow = Bb + (size_t)i * NTOK;
        const int j0 = i + lane;
        float mv[32];
        float mn = FLT_MAX;
#pragma unroll
        for (int c = 0; c < 32; ++c) {
            const int j = j0 + c * 64;
            float v = FLT_MAX;
            if (j < jmax) v = brow[j] + cs[j];
            mv[c] = v;
            mn = fminf(mn, v);
        }
#pragma unroll
        for (int off = 32; off; off >>= 1) mn = fminf(mn, __shfl_xor(mn, off));
        if (lane == 0) Cn[i] = mn;
        float s = 0.0f;
#pragma unroll
        for (int c = 0; c < 32; ++c) {
            const int j = j0 + c * 64;
            float p = 0.0f;
            if (j < jmax) p = __expf(mn - mv[c]);
            mv[c] = p;
            s += p;
        }
#pragma unroll
        for (int off = 32; off; off >>= 1) s += __shfl_xor(s, off);
        const float inv = 1.0f / s;
#pragma unroll
        for (int c = 0; c < 32; ++c) {
            const int j = j0 + c * 64;
            if (j < jmax) atomicAdd(&acc[j], mv[c] * inv);
        }
    }
    __syncthreads();
    float* ts = tsum + b * NTOK;
    for (int j = t; j < NTOK; j += 256) {
        const float v = acc[j];
        if (v != 0.0f) atomicAdd(&ts[j], v);
    }
}

__global__ void finalize_kernel(const float* __restrict__ tsum, float* __restrict__ out)
{
    const int b = blockIdx.y;
    const int j = blockIdx.x * 256 + threadIdx.x;
    if (j >= NTOK) return;
    float ts = tsum[b * NTOK + j];
    int steps = NTOK - 1 - j;
    if (steps > KSEG - 1) steps = KSEG - 1;
    float tc = (float)(j + 1) * (float)steps;
    if (j == NTOK - 1) { ts += (float)NTOK; tc += (float)NTOK; }
    out[b * NTOK + j] = ts / tc;
}

extern "C" void kernel_launch(void* const* d_in, const int* in_sizes, int n_in,
                              void* d_out, int out_size, void* d_ws, size_t ws_size,
                              hipStream_t stream)
{
    const float* x  = (const float*)d_in[0];
    const float* W0 = (const float*)d_in[1];
    const float* b0 = (const float*)d_in[2];
    const float* W1 = (const float*)d_in[3];
    const float* b1 = (const float*)d_in[4];
    float* out = (float*)d_out;

    char* ws = (char*)d_ws;
    size_t off = 0;
    auto alloc = [&](size_t bytes) -> void* {
        void* p = (void*)(ws + off);
        off += (bytes + 255) & ~(size_t)255;
        return p;
    };
    double* Sp   = (double*)alloc((size_t)BATCH * ST2 * sizeof(double));
    float*  Dm   = (float*) alloc((size_t)BATCH * NTOK * NTOK * sizeof(float));
    float*  h    = (float*) alloc((size_t)BATCH * NTOK * HDIM * sizeof(float));
    float*  e    = (float*) alloc((size_t)BATCH * NTOK * EDIM * sizeof(float));
    float*  dvec = (float*) alloc((size_t)BATCH * NTOK * sizeof(float));
    double* dg   = (double*)alloc((size_t)BATCH * NP1 * sizeof(double));
    double* aux  = (double*)alloc((size_t)BATCH * 8 * NP1 * sizeof(double));
    float*  CA   = (float*) alloc((size_t)BATCH * NTOK * sizeof(float));
    float*  CB   = (float*) alloc((size_t)BATCH * NTOK * sizeof(float));
    float*  tsum = (float*) alloc((size_t)BATCH * NTOK * sizeof(float));
    int*    flags= (int*)   alloc((size_t)BATCH * DP_BX * 4 * sizeof(int));
    (void)ws_size; (void)in_sizes; (void)n_in; (void)out_size;

    hipMemsetAsync(tsum, 0, (size_t)BATCH * NTOK * sizeof(float), stream);
    hipMemsetAsync(flags, 0xFF, (size_t)BATCH * DP_BX * 4 * sizeof(int), stream);  // -1

    gemm_nt<0><<<dim3(HDIM / 64, (BATCH * NTOK) / 64, 1), 256, 0, stream>>>(
        x, FDIM, 0, W0, FDIM, 0, b0, h, HDIM, 0, FDIM, nullptr);
    gemm_nt<1><<<dim3(EDIM / 64, (BATCH * NTOK) / 64, 1), 256, 0, stream>>>(
        h, HDIM, 0, W1, HDIM, 0, b1, e, EDIM, 0, HDIM, nullptr);
    rownorm_kernel<<<dim3((BATCH * NTOK) / 4), 256, 0, stream>>>(e, dvec);
    gemm_nt<2><<<dim3(NTOK / 64, NTOK / 64, BATCH), 256, 0, stream>>>(
        e, EDIM, (size_t)NTOK * EDIM, e, EDIM, (size_t)NTOK * EDIM, nullptr,
        Dm, NTOK, (size_t)NTOK * NTOK, EDIM, dvec);
    sat_row_kernel<<<dim3(NTOK, BATCH), 256, 0, stream>>>(Dm, Sp);
    satc1<<<dim3((NP1 + 255) / 256, 8, BATCH), 256, 0, stream>>>(Sp, aux);
    satc2<<<dim3((NP1 + 255) / 256, BATCH), 256, 0, stream>>>(aux);
    satc3<<<dim3((NP1 + 255) / 256, 8, BATCH), 256, 0, stream>>>(Sp, aux);
    diag_kernel<<<dim3((NP1 + 255) / 256, BATCH), 256, 0, stream>>>(Sp, dg);
    bsum_kernel<<<dim3(NTOK, BATCH), 256, 0, stream>>>(Sp, dg, Dm, CA);

    // Fused DP (cooperative launch for co-residency; flag-array sync inside).
    void* args[] = { (void*)&Dm, (void*)&CA, (void*)&CB, (void*)&tsum, (void*)&flags };
    hipError_t err = hipLaunchCooperativeKernel((const void*)dp_fused_kernel,
                                                dim3(DP_BX, BATCH), dim3(256),
                                                args, 0, stream);
    if (err != hipSuccess) {
        // fallback: 29 separate step launches (CA already holds C0 from bsum_kernel)
        float* cp = CA; float* cn = CB;
        for (int kk = 1; kk < KSEG; ++kk) {
            dp_step_kernel<<<dim3(128, BATCH), 256, 0, stream>>>(Dm, cp, cn, tsum, kk);
            float* tmp = cp; cp = cn; cn = tmp;
        }
    }
    finalize_kernel<<<dim3(NTOK / 256, BATCH), 256, 0, stream>>>(tsum, out);
}

// Round 6
// 1258.653 us; speedup vs baseline: 1.2360x; 1.2360x over previous
//
#include <hip/hip_runtime.h>
#include <hip/hip_bf16.h>
#include <float.h>

// Problem constants (OSG_C_29987461660961)
#define NTOK 2048
#define FDIM 1024
#define HDIM 512
#define EDIM 256
#define BATCH 2
#define KSEG 30
#define NP1 2049
static const size_t ST2 = (size_t)NP1 * NP1;   // Sp per-batch element count

// ---------------------------------------------------------------------------
// Shared NT GEMM: C[i][j] = sum_k A[i*lda+k]*B[j*ldb+k]  (+bias / relu / D-xform)
// ---------------------------------------------------------------------------
template<int MODE>
__global__ __launch_bounds__(256)
void gemm_nt(const float* __restrict__ A, int lda, size_t strideA,
             const float* __restrict__ Bm, int ldb, size_t strideB,
             const float* __restrict__ bias,
             float* __restrict__ C, int ldc, size_t strideC,
             int K, const float* __restrict__ dvec)
{
    __shared__ float As[32][68];
    __shared__ float Bs[32][68];
    const int z = blockIdx.z;
    const float* Ab = A + (size_t)z * strideA;
    const float* Bb = Bm + (size_t)z * strideB;
    float* Cb = C + (size_t)z * strideC;

    const int t = threadIdx.x;
    const int tx = t & 15, ty = t >> 4;
    const int lrow = t >> 3, lkv = t & 7;
    const int by = blockIdx.y, bx = blockIdx.x;

    float acc[4][4] = {};
    const int ktiles = K >> 5;
    for (int kt = 0; kt < ktiles; ++kt) {
#pragma unroll
        for (int h = 0; h < 2; ++h) {
            const int r = lrow + h * 32;
            const float4 av = *(const float4*)(Ab + (size_t)(by * 64 + r) * lda + kt * 32 + lkv * 4);
            As[lkv * 4 + 0][r] = av.x; As[lkv * 4 + 1][r] = av.y;
            As[lkv * 4 + 2][r] = av.z; As[lkv * 4 + 3][r] = av.w;
            const float4 bv = *(const float4*)(Bb + (size_t)(bx * 64 + r) * ldb + kt * 32 + lkv * 4);
            Bs[lkv * 4 + 0][r] = bv.x; Bs[lkv * 4 + 1][r] = bv.y;
            Bs[lkv * 4 + 2][r] = bv.z; Bs[lkv * 4 + 3][r] = bv.w;
        }
        __syncthreads();
#pragma unroll
        for (int kk = 0; kk < 32; ++kk) {
            const float4 a = *(const float4*)&As[kk][ty * 4];
            const float4 b = *(const float4*)&Bs[kk][tx * 4];
            const float ar[4] = {a.x, a.y, a.z, a.w};
            const float br[4] = {b.x, b.y, b.z, b.w};
#pragma unroll
            for (int i = 0; i < 4; ++i)
#pragma unroll
                for (int j = 0; j < 4; ++j)
                    acc[i][j] = fmaf(ar[i], br[j], acc[i][j]);
        }
        __syncthreads();
    }

    const int row0 = by * 64 + ty * 4;
    const int col0 = bx * 64 + tx * 4;
    if (MODE == 2) {
        float di[4], dj[4];
#pragma unroll
        for (int i = 0; i < 4; ++i) di[i] = dvec[z * NTOK + row0 + i];
#pragma unroll
        for (int j = 0; j < 4; ++j) dj[j] = dvec[z * NTOK + col0 + j];
#pragma unroll
        for (int i = 0; i < 4; ++i) {
            float4 v;
            float o[4];
#pragma unroll
            for (int j = 0; j < 4; ++j) {
                const float den = sqrtf(fmaxf(di[i] * dj[j], 1e-8f));
                o[j] = 0.5f * (1.0f - acc[i][j] / den);
            }
            v.x = o[0]; v.y = o[1]; v.z = o[2]; v.w = o[3];
            *(float4*)(Cb + (size_t)(row0 + i) * ldc + col0) = v;
        }
    } else {
#pragma unroll
        for (int i = 0; i < 4; ++i) {
            float o[4];
#pragma unroll
            for (int j = 0; j < 4; ++j) {
                float v = acc[i][j] + bias[col0 + j];
                if (MODE == 0) v = fmaxf(v, 0.0f);
                o[j] = v;
            }
            float4 v4; v4.x = o[0]; v4.y = o[1]; v4.z = o[2]; v4.w = o[3];
            *(float4*)(Cb + (size_t)(row0 + i) * ldc + col0) = v4;
        }
    }
}

__global__ __launch_bounds__(256)
void rownorm_kernel(const float* __restrict__ e, float* __restrict__ dvec)
{
    const int wid = (blockIdx.x * 256 + threadIdx.x) >> 6;
    const int lane = threadIdx.x & 63;
    if (wid >= BATCH * NTOK) return;
    const float4 v = *(const float4*)(e + (size_t)wid * EDIM + lane * 4);
    float s = v.x * v.x + v.y * v.y + v.z * v.z + v.w * v.w;
#pragma unroll
    for (int off = 32; off; off >>= 1) s += __shfl_xor(s, off);
    if (lane == 0) dvec[wid] = s;
}

// Row-wise inclusive scan of D (f32) into Sp rows 1..N (f64). Sp[r][0]=0.
__global__ __launch_bounds__(256)
void sat_row_kernel(const float* __restrict__ D, double* __restrict__ Sp)
{
    const int b = blockIdx.y;
    const int r = blockIdx.x + 1;
    const float* drow = D + (size_t)b * NTOK * NTOK + (size_t)(r - 1) * NTOK;
    double* sprow = Sp + (size_t)b * ST2 + (size_t)r * NP1;
    const int t = threadIdx.x, lane = t & 63, wv = t >> 6;
    __shared__ double wtot[4];
    double carry = 0.0;
    if (t == 0) sprow[0] = 0.0;
    for (int ch = 0; ch < NTOK / 256; ++ch) {
        double v = (double)drow[ch * 256 + t];
#pragma unroll
        for (int d = 1; d < 64; d <<= 1) {
            const double u = __shfl_up(v, (unsigned)d, 64);
            if (lane >= d) v += u;
        }
        if (lane == 63) wtot[wv] = v;
        __syncthreads();
        double pre = carry;
        for (int ww = 0; ww < wv; ++ww) pre += wtot[ww];
        const double tot = carry + wtot[0] + wtot[1] + wtot[2] + wtot[3];
        sprow[ch * 256 + t + 1] = v + pre;
        __syncthreads();
        carry = tot;
    }
}

// Column cumsum of Sp in 3 phases (strips of 256 rows).
__global__ void satc1(const double* __restrict__ Sp, double* __restrict__ aux)
{
    const int b = blockIdx.z, s = blockIdx.y;
    const int c = blockIdx.x * 256 + threadIdx.x;
    if (c > NTOK) return;
    const double* sp = Sp + (size_t)b * ST2;
    double tt = 0.0;
    const int r0 = s * 256 + 1;
    for (int r = r0; r < r0 + 256; ++r) tt += sp[(size_t)r * NP1 + c];
    aux[(size_t)(b * 8 + s) * NP1 + c] = tt;
}
__global__ void satc2(double* __restrict__ aux)
{
    const int b = blockIdx.y;
    const int c = blockIdx.x * 256 + threadIdx.x;
    if (c > NTOK) return;
    double run = 0.0;
    for (int s = 0; s < 8; ++s) {
        const size_t id = (size_t)(b * 8 + s) * NP1 + c;
        const double tt = aux[id]; aux[id] = run; run += tt;
    }
}
__global__ void satc3(double* __restrict__ Sp, const double* __restrict__ aux)
{
    const int b = blockIdx.z, s = blockIdx.y;
    const int c = blockIdx.x * 256 + threadIdx.x;
    if (c > NTOK) return;
    double* sp = Sp + (size_t)b * ST2;
    if (s == 0) sp[c] = 0.0;
    double run = aux[(size_t)(b * 8 + s) * NP1 + c];
    const int r0 = s * 256 + 1;
    for (int r = r0; r < r0 + 256; ++r) {
        const size_t id = (size_t)r * NP1 + c;
        run += sp[id];
        sp[id] = run;
    }
}

__global__ void diag_kernel(const double* __restrict__ Sp, double* __restrict__ dg)
{
    const int b = blockIdx.y;
    const int t = blockIdx.x * 256 + threadIdx.x;
    if (t <= NTOK) dg[b * NP1 + t] = Sp[(size_t)b * ST2 + (size_t)t * NP1 + t];
}

// Bsum[i][j] = diag[j+1] + diag[i] - 2*Sp[i][j+1] (f64 math -> f32), j >= i.
__global__ __launch_bounds__(256)
void bsum_kernel(const double* __restrict__ Sp, const double* __restrict__ dg,
                 float* __restrict__ Bsum, float* __restrict__ C0)
{
    const int b = blockIdx.y, i = blockIdx.x;
    const double* sprow = Sp + (size_t)b * ST2 + (size_t)i * NP1;
    const double* dgb = dg + (size_t)b * NP1;
    const double di = dgb[i];
    float* brow = Bsum + (size_t)b * NTOK * NTOK + (size_t)i * NTOK;
    for (int j = i + threadIdx.x; j < NTOK; j += 256) {
        const double v = dgb[j + 1] + di - 2.0 * sprow[j + 1];
        brow[j] = (float)v;
        if (j == NTOK - 1) C0[b * NTOK + i] = (float)v;
    }
}

// ---------------------------------------------------------------------------
// Fence-free flag sync. All cross-block data (C vector, flags) moves through
// agent-scope (sc1) atomics served at the MALL — L2 holds nothing for these
// addresses, so no buffer_wbl2 / buffer_inv is needed anywhere in the loop:
//   publish = __syncthreads() (drains each wave's vmcnt -> all cstores are at
//             the coherence point) + RELAXED flag store
//   wait    = RELAXED parallel poll (thread t polls block t's flag) + barrier
// ---------------------------------------------------------------------------
#define DP_BX 128
#define DP_PAIRS 8

__device__ inline void cstore(float* p, float v)
{
    __hip_atomic_store(p, v, __ATOMIC_RELAXED, __HIP_MEMORY_SCOPE_AGENT);
}
__device__ inline float cload(const float* p)
{
    return __hip_atomic_load(p, __ATOMIC_RELAXED, __HIP_MEMORY_SCOPE_AGENT);
}

__device__ inline void wait_flags(const int* flagsb, int need)
{
    const int t = threadIdx.x;
    if (t < DP_BX) {
        const int* f = flagsb + t * 4;
        while (__hip_atomic_load(f, __ATOMIC_RELAXED, __HIP_MEMORY_SCOPE_AGENT) < need)
            __builtin_amdgcn_s_sleep(1);
    }
    asm volatile("" ::: "memory");
    __syncthreads();           // no acquire fence: flag+data live at MALL
}

__device__ inline void publish(int* myflag, int val)
{
    asm volatile("s_waitcnt vmcnt(0)" ::: "memory");  // belt & braces (syncthreads also drains)
    __syncthreads();
    if (threadIdx.x == 0)
        __hip_atomic_store(myflag, val, __ATOMIC_RELAXED, __HIP_MEMORY_SCOPE_AGENT);
}

// min pass: fill mv[] with Bsum+Cshift, return wave-reduced row min
template<int NC>
__device__ inline float minpass(const float* __restrict__ rb, const float* __restrict__ csv,
                                int coff, int V, int lane, float (&mv)[NC])
{
    float mn = FLT_MAX;
#pragma unroll
    for (int c = 0; c < NC; ++c) {
        const int idx = lane + c * 64;
        float v = FLT_MAX;
        if (idx < V) v = rb[idx] + csv[coff + idx];
        mv[c] = v;
        mn = fminf(mn, v);
    }
#pragma unroll
    for (int o = 32; o; o >>= 1) mn = fminf(mn, __shfl_xor(mn, o));
    return mn;
}

// exp pass: softmax weights from saved mv/mn, accumulate into LDS acc
template<int NC>
__device__ inline void exppass(float (&mv)[NC], float mn, int V, int lane,
                               float* __restrict__ accb)
{
    float s = 0.0f;
#pragma unroll
    for (int c = 0; c < NC; ++c) {
        const int idx = lane + c * 64;
        float w = 0.0f;
        if (idx < V) w = __expf(mn - mv[c]);
        mv[c] = w;
        s += w;
    }
#pragma unroll
    for (int o = 32; o; o >>= 1) s += __shfl_xor(s, o);
    const float inv = 1.0f / s;
#pragma unroll
    for (int c = 0; c < NC; ++c) {
        const int idx = lane + c * 64;
        if (idx < V) atomicAdd(&accb[idx], mv[c] * inv);
    }
}

// ---------------------------------------------------------------------------
// Fused DP: all 29 steps, Bsum upper-triangle parked in LDS.
// Grid (128, BATCH) x 256 threads, 8 row pairs (p, 2047-p) per block,
// 82KB LDS -> 1 block/CU, 256 blocks co-resident (cooperative launch).
// Early-publish: flag goes up after min-pass + Cn store; the exp/accumulate
// pass runs in the sync shadow.
// ---------------------------------------------------------------------------
__global__ __launch_bounds__(256)
void dp_fused_kernel(const float* __restrict__ Bsum,
                     float* __restrict__ Ca, float* __restrict__ Cb,
                     float* __restrict__ tsum, int* __restrict__ flags)
{
    __shared__ float rowbuf[DP_PAIRS][2052];
    __shared__ float cs[NTOK];
    __shared__ float acc[NTOK];
    const int b = blockIdx.y;
    const int t = threadIdx.x, lane = t & 63, wv = t >> 6;
    const float* Bb = Bsum + (size_t)b * NTOK * NTOK;
    const int pbase = blockIdx.x * DP_PAIRS;
    int* flagsb = flags + b * DP_BX * 4;
    int* myflag = flagsb + blockIdx.x * 4;

    // coalesced whole-block load of each pair-row (row i0 cols p.., then row i1)
    for (int pr = 0; pr < DP_PAIRS; ++pr) {
        const int p = pbase + pr;
        const int L0 = NTOK - p;
        const float* r0 = Bb + (size_t)p * NTOK + p;
        const float* r1 = Bb + (size_t)(NTOK - 1 - p) * NTOK;
        for (int idx = t; idx <= NTOK; idx += 256)
            rowbuf[pr][idx] = (idx < L0) ? r0[idx] : r1[idx - 1];
    }
    for (int j = t; j < NTOK; j += 256) acc[j] = 0.0f;
    __syncthreads();
    // C0[i] = Bsum[i][N-1]
    for (int pr = t; pr < DP_PAIRS; pr += 256) {
        const int p = pbase + pr;
        cstore(&Ca[b * NTOK + p], rowbuf[pr][NTOK - p - 1]);
        cstore(&Ca[b * NTOK + (NTOK - 1 - p)], rowbuf[pr][NTOK]);
    }
    publish(myflag, 0);

    const float* Cr = Ca;
    float* Cn = Cb;
    const int p0 = pbase + wv * 2;
    const int p1 = p0 + 1;
    const float* rb0 = rowbuf[wv * 2];
    const float* rb1 = rowbuf[wv * 2 + 1];
    const int i1_0 = NTOK - 1 - p0, i1_1 = NTOK - 1 - p1;

    for (int k = 1; k < KSEG; ++k) {
        wait_flags(flagsb, k - 1);         // all blocks of batch b published step k-1
        const float* Crb = Cr + b * NTOK;
        for (int j = t; j < NTOK; j += 256)
            cs[j] = (j < NTOK - 1) ? cload(&Crb[j + 1]) : 0.0f;
        __syncthreads();
        const int jmax = NTOK - k;
        float* Cnb = Cn + b * NTOK;

        // ---- min phase (cross-block dependency) ----
        float mvA[32], mvB[16], mvC[32], mvD[16];
        const int VA = jmax - p0, VC = jmax - p1;
        const int VB = p0 + 1 - k, VD = p1 + 1 - k;
        const float mnA = minpass<32>(rb0, cs, p0, VA, lane, mvA);
        float mnB = 0.0f, mnD = 0.0f;
        if (p0 >= k) mnB = minpass<16>(rb0 + (NTOK - p0), cs, i1_0, VB, lane, mvB);
        const float mnC = minpass<32>(rb1, cs, p1, VC, lane, mvC);
        if (p1 >= k) mnD = minpass<16>(rb1 + (NTOK - p1), cs, i1_1, VD, lane, mvD);
        if (lane == 0) {
            cstore(&Cnb[p0], mnA);
            cstore(&Cnb[i1_0], (p0 >= k) ? mnB : 0.0f);
            cstore(&Cnb[p1], mnC);
            cstore(&Cnb[i1_1], (p1 >= k) ? mnD : 0.0f);
        }
        publish(myflag, k);                // early: exp pass needs no Cr/Cn access

        // ---- exp/accumulate phase (LDS only, hides under sync skew) ----
        exppass<32>(mvA, mnA, VA, lane, acc + p0);
        if (p0 >= k) exppass<16>(mvB, mnB, VB, lane, acc + i1_0);
        exppass<32>(mvC, mnC, VC, lane, acc + p1);
        if (p1 >= k) exppass<16>(mvD, mnD, VD, lane, acc + i1_1);

        float* tmp = (float*)Cr; Cr = Cn; Cn = tmp;
    }
    // merge per-block acc into global tsum
    __syncthreads();
    float* ts = tsum + b * NTOK;
    for (int j = t; j < NTOK; j += 256) {
        const float v = acc[j];
        if (v != 0.0f) atomicAdd(&ts[j], v);
    }
}

// ---- fallback path (29 launches), kept in case cooperative launch fails ----
__global__ __launch_bounds__(256)
void dp_step_kernel(const float* __restrict__ Bsum, const float* __restrict__ Cprev,
                    float* __restrict__ Cnext, float* __restrict__ tsum, int kk)
{
    __shared__ float cs[NTOK];
    __shared__ float acc[NTOK];
    const int b = blockIdx.y;
    const int t = threadIdx.x, lane = t & 63, wv = t >> 6;
    const float* Cp = Cprev + b * NTOK;
    for (int j = t; j < NTOK; j += 256) {
        cs[j] = (j < NTOK - 1) ? Cp[j + 1] : 0.0f;
        acc[j] = 0.0f;
    }
    __syncthreads();
    const int jmax = NTOK - kk;
    const int w = blockIdx.x * 4 + wv;
    const float* Bb = Bsum + (size_t)b * NTOK * NTOK;
    float* Cn = Cnext + b * NTOK;
    const int rows[4] = { w, 1023 - w, 1024 + w, 2047 - w };
#pragma unroll
    for (int rr = 0; rr < 4; ++rr) {
        const int i = rows[rr];
        if (i >= jmax) { if (lane == 0) Cn[i] = 0.0f; continue; }
        const float* brow = Bb + (size_t)i * NTOK;
        const int j0 = i + lane;
        float mv[32];
        float mn = FLT_MAX;
#pragma unroll
        for (int c = 0; c < 32; ++c) {
            const int j = j0 + c * 64;
            float v = FLT_MAX;
            if (j < jmax) v = brow[j] + cs[j];
            mv[c] = v;
            mn = fminf(mn, v);
        }
#pragma unroll
        for (int off = 32; off; off >>= 1) mn = fminf(mn, __shfl_xor(mn, off));
        if (lane == 0) Cn[i] = mn;
        float s = 0.0f;
#pragma unroll
        for (int c = 0; c < 32; ++c) {
            const int j = j0 + c * 64;
            float p = 0.0f;
            if (j < jmax) p = __expf(mn - mv[c]);
            mv[c] = p;
            s += p;
        }
#pragma unroll
        for (int off = 32; off; off >>= 1) s += __shfl_xor(s, off);
        const float inv = 1.0f / s;
#pragma unroll
        for (int c = 0; c < 32; ++c) {
            const int j = j0 + c * 64;
            if (j < jmax) atomicAdd(&acc[j], mv[c] * inv);
        }
    }
    __syncthreads();
    float* ts = tsum + b * NTOK;
    for (int j = t; j < NTOK; j += 256) {
        const float v = acc[j];
        if (v != 0.0f) atomicAdd(&ts[j], v);
    }
}

__global__ void finalize_kernel(const float* __restrict__ tsum, float* __restrict__ out)
{
    const int b = blockIdx.y;
    const int j = blockIdx.x * 256 + threadIdx.x;
    if (j >= NTOK) return;
    float ts = tsum[b * NTOK + j];
    int steps = NTOK - 1 - j;
    if (steps > KSEG - 1) steps = KSEG - 1;
    float tc = (float)(j + 1) * (float)steps;
    if (j == NTOK - 1) { ts += (float)NTOK; tc += (float)NTOK; }
    out[b * NTOK + j] = ts / tc;
}

extern "C" void kernel_launch(void* const* d_in, const int* in_sizes, int n_in,
                              void* d_out, int out_size, void* d_ws, size_t ws_size,
                              hipStream_t stream)
{
    const float* x  = (const float*)d_in[0];
    const float* W0 = (const float*)d_in[1];
    const float* b0 = (const float*)d_in[2];
    const float* W1 = (const float*)d_in[3];
    const float* b1 = (const float*)d_in[4];
    float* out = (float*)d_out;

    char* ws = (char*)d_ws;
    size_t off = 0;
    auto alloc = [&](size_t bytes) -> void* {
        void* p = (void*)(ws + off);
        off += (bytes + 255) & ~(size_t)255;
        return p;
    };
    double* Sp   = (double*)alloc((size_t)BATCH * ST2 * sizeof(double));
    float*  Dm   = (float*) alloc((size_t)BATCH * NTOK * NTOK * sizeof(float));
    float*  h    = (float*) alloc((size_t)BATCH * NTOK * HDIM * sizeof(float));
    float*  e    = (float*) alloc((size_t)BATCH * NTOK * EDIM * sizeof(float));
    float*  dvec = (float*) alloc((size_t)BATCH * NTOK * sizeof(float));
    double* dg   = (double*)alloc((size_t)BATCH * NP1 * sizeof(double));
    double* aux  = (double*)alloc((size_t)BATCH * 8 * NP1 * sizeof(double));
    float*  CA   = (float*) alloc((size_t)BATCH * NTOK * sizeof(float));
    float*  CB   = (float*) alloc((size_t)BATCH * NTOK * sizeof(float));
    float*  tsum = (float*) alloc((size_t)BATCH * NTOK * sizeof(float));
    int*    flags= (int*)   alloc((size_t)BATCH * DP_BX * 4 * sizeof(int));
    (void)ws_size; (void)in_sizes; (void)n_in; (void)out_size;

    hipMemsetAsync(tsum, 0, (size_t)BATCH * NTOK * sizeof(float), stream);
    hipMemsetAsync(flags, 0xFF, (size_t)BATCH * DP_BX * 4 * sizeof(int), stream);  // -1

    gemm_nt<0><<<dim3(HDIM / 64, (BATCH * NTOK) / 64, 1), 256, 0, stream>>>(
        x, FDIM, 0, W0, FDIM, 0, b0, h, HDIM, 0, FDIM, nullptr);
    gemm_nt<1><<<dim3(EDIM / 64, (BATCH * NTOK) / 64, 1), 256, 0, stream>>>(
        h, HDIM, 0, W1, HDIM, 0, b1, e, EDIM, 0, HDIM, nullptr);
    rownorm_kernel<<<dim3((BATCH * NTOK) / 4), 256, 0, stream>>>(e, dvec);
    gemm_nt<2><<<dim3(NTOK / 64, NTOK / 64, BATCH), 256, 0, stream>>>(
        e, EDIM, (size_t)NTOK * EDIM, e, EDIM, (size_t)NTOK * EDIM, nullptr,
        Dm, NTOK, (size_t)NTOK * NTOK, EDIM, dvec);
    sat_row_kernel<<<dim3(NTOK, BATCH), 256, 0, stream>>>(Dm, Sp);
    satc1<<<dim3((NP1 + 255) / 256, 8, BATCH), 256, 0, stream>>>(Sp, aux);
    satc2<<<dim3((NP1 + 255) / 256, BATCH), 256, 0, stream>>>(aux);
    satc3<<<dim3((NP1 + 255) / 256, 8, BATCH), 256, 0, stream>>>(Sp, aux);
    diag_kernel<<<dim3((NP1 + 255) / 256, BATCH), 256, 0, stream>>>(Sp, dg);
    bsum_kernel<<<dim3(NTOK, BATCH), 256, 0, stream>>>(Sp, dg, Dm, CA);

    // Fused DP (cooperative launch for co-residency; fence-free flag sync inside).
    void* args[] = { (void*)&Dm, (void*)&CA, (void*)&CB, (void*)&tsum, (void*)&flags };
    hipError_t err = hipLaunchCooperativeKernel((const void*)dp_fused_kernel,
                                                dim3(DP_BX, BATCH), dim3(256),
                                                args, 0, stream);
    if (err != hipSuccess) {
        // fallback: 29 separate step launches (CA already holds C0 from bsum_kernel)
        float* cp = CA; float* cn = CB;
        for (int kk = 1; kk < KSEG; ++kk) {
            dp_step_kernel<<<dim3(128, BATCH), 256, 0, stream>>>(Dm, cp, cn, tsum, kk);
            float* tmp = cp; cp = cn; cn = tmp;
        }
    }
    finalize_kernel<<<dim3(NTOK / 256, BATCH), 256, 0, stream>>>(tsum, out);
}